// Round 1
// baseline (5708.801 us; speedup 1.0000x reference)
//
#include <hip/hip_runtime.h>
#include <math.h>

// Problem constants (from reference)
#define B_ 32
#define N_ 16384
#define K_ 21
#define C_ 64
#define M_ (N_ - K_ + 1)   // 16364
#define T_ 30
// L = 10.0, LAM = 0.1  ->  1/L = 0.1, LAM/L = 0.01

#define TA 1024    // positions per tile
#define CC 16      // channel chunk staged in LDS (convT)
#define CGB 16     // channels per block (update)
#define NTHR 256

// res[b,n] = use_y*y[b,n] + sign * sum_{c,j} X[b,c,n-j] * H[c,j]
__global__ __launch_bounds__(NTHR) void convT_kernel(
    const float* __restrict__ X, const float* __restrict__ y,
    const float* __restrict__ Hg, float* __restrict__ out,
    const int use_y, const float sign)
{
  __shared__ float xs[CC][TA + 20];   // 16 x 1044 floats = 66816 B
  __shared__ float hs[C_][K_];        // 5376 B (sign folded in)
  const int tid = threadIdx.x;
  const int b = blockIdx.y;
  const int n0 = blockIdx.x * TA;

  for (int f = tid; f < C_ * K_; f += NTHR) hs[f / K_][f % K_] = sign * Hg[f];

  float acc[4];
  if (use_y) {
    const float4 v = *(const float4*)(y + (size_t)b * N_ + n0 + tid * 4);
    acc[0] = v.x; acc[1] = v.y; acc[2] = v.z; acc[3] = v.w;
  } else {
    acc[0] = acc[1] = acc[2] = acc[3] = 0.f;
  }

  const bool interior = (n0 >= 20) && (n0 + TA - 1 <= M_ - 1);
  const int QROW = (TA + 20) / 4;   // 261 float4 per row

  for (int cb = 0; cb < C_; cb += CC) {
    __syncthreads();
    // stage x_tmp chunk [CC][TA+20] (zero-padded outside [0,M))
    for (int f = tid; f < CC * QROW; f += NTHR) {
      const int c = f / QROW;
      const int i = (f % QROW) * 4;
      const int gx = n0 - 20 + i;
      const float* src = X + ((size_t)(b * C_ + cb + c)) * M_ + gx;
      float4 v;
      if (interior) {
        v = *(const float4*)src;
      } else {
        v.x = (gx >= 0     && gx < M_)     ? src[0] : 0.f;
        v.y = (gx + 1 >= 0 && gx + 1 < M_) ? src[1] : 0.f;
        v.z = (gx + 2 >= 0 && gx + 2 < M_) ? src[2] : 0.f;
        v.w = (gx + 3 >= 0 && gx + 3 < M_) ? src[3] : 0.f;
      }
      *(float4*)&xs[c][i] = v;
    }
    __syncthreads();

    for (int c = 0; c < CC; ++c) {
      float w[24];  // sliding window: 4 outputs x 21 taps -> 24 inputs
      #pragma unroll
      for (int k = 0; k < 6; ++k) {
        const float4 v = *(const float4*)&xs[c][tid * 4 + k * 4];
        w[k*4] = v.x; w[k*4+1] = v.y; w[k*4+2] = v.z; w[k*4+3] = v.w;
      }
      const float* hr = hs[cb + c];
      #pragma unroll
      for (int j = 0; j < K_; ++j) {
        const float h = hr[j];
        acc[0] = fmaf(h, w[20 - j], acc[0]);
        acc[1] = fmaf(h, w[21 - j], acc[1]);
        acc[2] = fmaf(h, w[22 - j], acc[2]);
        acc[3] = fmaf(h, w[23 - j], acc[3]);
      }
    }
  }

  *(float4*)(out + (size_t)b * N_ + n0 + tid * 4) =
      make_float4(acc[0], acc[1], acc[2], acc[3]);
}

// For channels [c0,c0+CGB):
//   g[m]    = sum_j res[b,m+j] * H[c,j]
//   x_new   = relu(x_tmp + g/L - LAM/L)           (XN holds x_old on input)
//   x_tmp'  = x_new + beta*(x_new - x_old)
__global__ __launch_bounds__(NTHR) void update_kernel(
    const float* __restrict__ res, const float* __restrict__ Hg,
    float* __restrict__ XN, float* __restrict__ XT,
    const float beta, const int first)
{
  __shared__ float rs[TA + 20];
  __shared__ float hs[CGB][K_];
  const int tid = threadIdx.x;
  const int b = blockIdx.y;
  const int m0 = blockIdx.x * TA;
  const int c0 = blockIdx.z * CGB;

  for (int f = tid; f < CGB * K_; f += NTHR)
    hs[f / K_][f % K_] = Hg[(c0 + f / K_) * K_ + f % K_];

  const float* rrow = res + (size_t)b * N_;
  for (int q = tid; q < (TA + 20) / 4; q += NTHR) {
    const int i = q * 4;
    const int n = m0 + i;
    float4 v;
    if (n + 3 < N_) {
      v = *(const float4*)(rrow + n);
    } else {
      v.x = (n     < N_) ? rrow[n]     : 0.f;
      v.y = (n + 1 < N_) ? rrow[n + 1] : 0.f;
      v.z = (n + 2 < N_) ? rrow[n + 2] : 0.f;
      v.w = (n + 3 < N_) ? rrow[n + 3] : 0.f;
    }
    *(float4*)&rs[i] = v;
  }
  __syncthreads();

  const int m = m0 + tid * 4;
  if (m >= M_) return;   // M_ % 4 == 0, so in-range threads are fully in-range

  float w[24];
  #pragma unroll
  for (int k = 0; k < 6; ++k) {
    const float4 v = *(const float4*)&rs[tid * 4 + k * 4];
    w[k*4] = v.x; w[k*4+1] = v.y; w[k*4+2] = v.z; w[k*4+3] = v.w;
  }

  for (int cl = 0; cl < CGB; ++cl) {
    const int c = c0 + cl;
    const size_t base = ((size_t)(b * C_ + c)) * M_ + m;
    float g[4] = {0.f, 0.f, 0.f, 0.f};
    const float* hr = hs[cl];
    #pragma unroll
    for (int j = 0; j < K_; ++j) {
      const float h = hr[j];
      g[0] = fmaf(h, w[j],     g[0]);
      g[1] = fmaf(h, w[j + 1], g[1]);
      g[2] = fmaf(h, w[j + 2], g[2]);
      g[3] = fmaf(h, w[j + 3], g[3]);
    }
    float xt[4] = {0.f,0.f,0.f,0.f}, xo[4] = {0.f,0.f,0.f,0.f};
    if (!first) {
      const float4 a = *(const float4*)(XT + base);
      const float4 o = *(const float4*)(XN + base);
      xt[0]=a.x; xt[1]=a.y; xt[2]=a.z; xt[3]=a.w;
      xo[0]=o.x; xo[1]=o.y; xo[2]=o.z; xo[3]=o.w;
    }
    float xn[4], xtn[4];
    #pragma unroll
    for (int r = 0; r < 4; ++r) {
      const float v = fmaf(g[r], 0.1f, xt[r]) - 0.01f;  // x_tmp + g/L - LAM/L
      xn[r]  = v > 0.f ? v : 0.f;
      xtn[r] = xn[r] + beta * (xn[r] - xo[r]);
    }
    *(float4*)(XN + base) = make_float4(xn[0], xn[1], xn[2], xn[3]);
    *(float4*)(XT + base) = make_float4(xtn[0], xtn[1], xtn[2], xtn[3]);
  }
}

extern "C" void kernel_launch(void* const* d_in, const int* in_sizes, int n_in,
                              void* d_out, int out_size, void* d_ws, size_t ws_size,
                              hipStream_t stream)
{
  const float* y = (const float*)d_in[0];   // [B,1,N] fp32
  const float* H = (const float*)d_in[1];   // [C,1,K] fp32
  float* out = (float*)d_out;
  float* RES = out;                          // [B,N] region (y_hat; reused as res scratch)
  float* XN  = out + (size_t)B_ * N_;        // [B,C,M] region (x_old/x_new in place)
  float* XT  = (float*)d_ws;                 // [B,C,M] x_tmp, 134 MB of scratch

  // FISTA momentum scalars (host, deterministic)
  float betas[T_];
  double s = 1.0;
  for (int t = 0; t < T_; ++t) {
    const double sn = (1.0 + sqrt(1.0 + 4.0 * s * s)) * 0.5;
    betas[t] = (float)((s - 1.0) / sn);   // betas[0] = 0
    s = sn;
  }

  const dim3 blk(NTHR);
  const dim3 gA(N_ / TA, B_);                       // 16 x 32
  const dim3 gB((M_ + TA - 1) / TA, B_, C_ / CGB);  // 16 x 32 x 4

  // t=1: x_tmp = x_old = 0  =>  res = y; beta_1 = 0. No memset needed.
  update_kernel<<<gB, blk, 0, stream>>>(y, H, XN, XT, betas[0], 1);
  for (int t = 1; t < T_; ++t) {
    convT_kernel<<<gA, blk, 0, stream>>>(XT, y, H, RES, 1, -1.f);
    update_kernel<<<gB, blk, 0, stream>>>(RES, H, XN, XT, betas[t], 0);
  }
  // y_hat = convT(x_new)
  convT_kernel<<<gA, blk, 0, stream>>>(XN, y, H, RES, 0, 1.f);
}

// Round 2
// 4895.042 us; speedup vs baseline: 1.1662x; 1.1662x over previous
//
#include <hip/hip_runtime.h>
#include <math.h>

// Problem constants (from reference)
#define B_ 32
#define N_ 16384
#define K_ 21
#define C_ 64
#define M_ (N_ - K_ + 1)   // 16364
#define T_ 30
// L = 10.0, LAM = 0.1  ->  1/L = 0.1, LAM/L = 0.01

// ---------------- fused FISTA step kernel ----------------
// One block: batch b, position tile [n0, n0+TAF), ALL 64 channels.
//   x_tmp = Xc + beta*(Xc - Xo)            (reconstructed into LDS)
//   res   = y - convT(x_tmp)               (this tile + halo, all channels)
//   Xw    = relu(x_tmp + conv(res)/L - LAM/L)
#define TAF 236            // output positions per block
#define RW  256            // res positions per block  (TAF+20)
#define XWID 276           // x_tmp width staged       (TAF+40), = 4*69
#define NT  256

__global__ __launch_bounds__(NT) void fused_step_kernel(
    const float* __restrict__ Xc, const float* __restrict__ Xo,
    float* __restrict__ Xw, const float* __restrict__ y,
    const float* __restrict__ Hg, const float beta, const int first)
{
  __shared__ float xs[C_][XWID];   // 70656 B  x_tmp, all channels
  __shared__ float hs[C_][K_];     //  5376 B
  __shared__ float rp[4][RW];      //  4096 B  per-wave residual partials; rp[0] = final res
  const int tid = threadIdx.x;
  const int wv  = tid >> 6;        // wave 0..3 -> channels [16wv, 16wv+16)
  const int l   = tid & 63;        // lane -> 4 positions [4l, 4l+4)
  const int b   = blockIdx.y;
  const int n0  = blockIdx.x * TAF;
  const int g0  = n0 - 20;

  for (int f = tid; f < C_ * K_; f += NT) hs[f / K_][f % K_] = Hg[f];

  // ---- phase 1: reconstruct x_tmp into LDS ----
  if (!first) {
    const bool interior = (g0 >= 0) && (g0 + XWID <= M_);
    const bool has_o = (beta != 0.f);
    for (int f = tid; f < C_ * (XWID / 4); f += NT) {
      const int c = f / (XWID / 4);
      const int i = (f % (XWID / 4)) * 4;
      const int g = g0 + i;
      const float* pc = Xc + (size_t)(b * C_ + c) * M_;
      const float* po = Xo + (size_t)(b * C_ + c) * M_;
      float xc[4], xo[4];
      if (interior) {
        const float4 a = *(const float4*)(pc + g);
        xc[0]=a.x; xc[1]=a.y; xc[2]=a.z; xc[3]=a.w;
        if (has_o) {
          const float4 o = *(const float4*)(po + g);
          xo[0]=o.x; xo[1]=o.y; xo[2]=o.z; xo[3]=o.w;
        } else { xo[0]=xo[1]=xo[2]=xo[3]=0.f; }
      } else {
        #pragma unroll
        for (int e = 0; e < 4; ++e) {
          const int ge = g + e;
          const bool ok = (ge >= 0) && (ge < M_);
          xc[e] = ok ? pc[ge] : 0.f;
          xo[e] = (ok && has_o) ? po[ge] : 0.f;
        }
      }
      float v[4];
      #pragma unroll
      for (int e = 0; e < 4; ++e) v[e] = fmaf(beta, xc[e] - xo[e], xc[e]);
      *(float4*)&xs[c][i] = make_float4(v[0], v[1], v[2], v[3]);
    }
  }
  __syncthreads();

  // ---- phase 2: residual partials (wave wv covers 16 channels) ----
  // res[n] = y[n] - sum_c sum_j x_tmp[c][n-j]*H[c,j]
  //        -> window xs[c][nl .. nl+20] (local coords incl. left halo of 20)
  if (!first) {
    float p0 = 0.f, p1 = 0.f, p2 = 0.f, p3 = 0.f;
    for (int cl = 0; cl < 16; ++cl) {
      const int c = wv * 16 + cl;
      float w24[24];
      #pragma unroll
      for (int k = 0; k < 6; ++k)
        *(float4*)&w24[4 * k] = *(const float4*)&xs[c][4 * l + 4 * k];
      const float* hr = hs[c];
      #pragma unroll
      for (int u = 0; u <= 20; ++u) {
        const float hv = hr[20 - u];
        p0 = fmaf(w24[u],     hv, p0);
        p1 = fmaf(w24[u + 1], hv, p1);
        p2 = fmaf(w24[u + 2], hv, p2);
        p3 = fmaf(w24[u + 3], hv, p3);
      }
    }
    *(float4*)&rp[wv][4 * l] = make_float4(p0, p1, p2, p3);
  }
  __syncthreads();

  // ---- phase 2b: finalize res into rp[0] ----
  {
    const int n = n0 + tid;
    const float yv = (n < N_) ? y[(size_t)b * N_ + n] : 0.f;
    float r = yv;
    if (!first) r = yv - (rp[0][tid] + rp[1][tid] + rp[2][tid] + rp[3][tid]);
    rp[0][tid] = r;   // each slot read+written by this thread only
  }
  __syncthreads();

  // ---- phase 3: gradient step + shrink, write x_{t+1} ----
  const int mf4 = (M_ - n0) / 4;              // always multiple of 4 remains
  const int af4 = (mf4 < 59) ? mf4 : 59;      // active float4 groups (59 or 20)
  if (l < af4) {
    float w24[24];
    #pragma unroll
    for (int k = 0; k < 6; ++k)
      *(float4*)&w24[4 * k] = *(const float4*)&rp[0][4 * l + 4 * k];
    for (int cl = 0; cl < 16; ++cl) {
      const int c = wv * 16 + cl;
      float xt[4] = {0.f, 0.f, 0.f, 0.f};
      if (!first) {
        const float4 a = *(const float4*)&xs[c][20 + 4 * l];
        xt[0]=a.x; xt[1]=a.y; xt[2]=a.z; xt[3]=a.w;
      }
      const float* hr = hs[c];
      float g[4] = {0.f, 0.f, 0.f, 0.f};
      #pragma unroll
      for (int j = 0; j <= 20; ++j) {
        const float hv = hr[j];
        g[0] = fmaf(w24[j],     hv, g[0]);
        g[1] = fmaf(w24[j + 1], hv, g[1]);
        g[2] = fmaf(w24[j + 2], hv, g[2]);
        g[3] = fmaf(w24[j + 3], hv, g[3]);
      }
      float o[4];
      #pragma unroll
      for (int e = 0; e < 4; ++e) {
        const float v = fmaf(g[e], 0.1f, xt[e]) - 0.01f;
        o[e] = v > 0.f ? v : 0.f;
      }
      *(float4*)(Xw + (size_t)(b * C_ + c) * M_ + n0 + 4 * l) =
          make_float4(o[0], o[1], o[2], o[3]);
    }
  }
}

// ---------------- convT kernel (final y_hat; also fallback) ----------------
#define TA 1024
#define CC 16
#define CGB 16
#define NTHR 256

__global__ __launch_bounds__(NTHR) void convT_kernel(
    const float* __restrict__ X, const float* __restrict__ y,
    const float* __restrict__ Hg, float* __restrict__ out,
    const int use_y, const float sign)
{
  __shared__ float xs[CC][TA + 20];
  __shared__ float hs[C_][K_];
  const int tid = threadIdx.x;
  const int b = blockIdx.y;
  const int n0 = blockIdx.x * TA;

  for (int f = tid; f < C_ * K_; f += NTHR) hs[f / K_][f % K_] = sign * Hg[f];

  float acc[4];
  if (use_y) {
    const float4 v = *(const float4*)(y + (size_t)b * N_ + n0 + tid * 4);
    acc[0] = v.x; acc[1] = v.y; acc[2] = v.z; acc[3] = v.w;
  } else {
    acc[0] = acc[1] = acc[2] = acc[3] = 0.f;
  }

  const bool interior = (n0 >= 20) && (n0 + TA - 1 <= M_ - 1);
  const int QROW = (TA + 20) / 4;

  for (int cb = 0; cb < C_; cb += CC) {
    __syncthreads();
    for (int f = tid; f < CC * QROW; f += NTHR) {
      const int c = f / QROW;
      const int i = (f % QROW) * 4;
      const int gx = n0 - 20 + i;
      const float* src = X + ((size_t)(b * C_ + cb + c)) * M_ + gx;
      float4 v;
      if (interior) {
        v = *(const float4*)src;
      } else {
        v.x = (gx >= 0     && gx < M_)     ? src[0] : 0.f;
        v.y = (gx + 1 >= 0 && gx + 1 < M_) ? src[1] : 0.f;
        v.z = (gx + 2 >= 0 && gx + 2 < M_) ? src[2] : 0.f;
        v.w = (gx + 3 >= 0 && gx + 3 < M_) ? src[3] : 0.f;
      }
      *(float4*)&xs[c][i] = v;
    }
    __syncthreads();

    for (int c = 0; c < CC; ++c) {
      float w[24];
      #pragma unroll
      for (int k = 0; k < 6; ++k) {
        const float4 v = *(const float4*)&xs[c][tid * 4 + k * 4];
        w[k*4] = v.x; w[k*4+1] = v.y; w[k*4+2] = v.z; w[k*4+3] = v.w;
      }
      const float* hr = hs[cb + c];
      #pragma unroll
      for (int j = 0; j < K_; ++j) {
        const float h = hr[j];
        acc[0] = fmaf(h, w[20 - j], acc[0]);
        acc[1] = fmaf(h, w[21 - j], acc[1]);
        acc[2] = fmaf(h, w[22 - j], acc[2]);
        acc[3] = fmaf(h, w[23 - j], acc[3]);
      }
    }
  }

  *(float4*)(out + (size_t)b * N_ + n0 + tid * 4) =
      make_float4(acc[0], acc[1], acc[2], acc[3]);
}

// ---------------- fallback update kernel (round-1 path) ----------------
__global__ __launch_bounds__(NTHR) void update_kernel(
    const float* __restrict__ res, const float* __restrict__ Hg,
    float* __restrict__ XN, float* __restrict__ XT,
    const float beta, const int first)
{
  __shared__ float rs[TA + 20];
  __shared__ float hs[CGB][K_];
  const int tid = threadIdx.x;
  const int b = blockIdx.y;
  const int m0 = blockIdx.x * TA;
  const int c0 = blockIdx.z * CGB;

  for (int f = tid; f < CGB * K_; f += NTHR)
    hs[f / K_][f % K_] = Hg[(c0 + f / K_) * K_ + f % K_];

  const float* rrow = res + (size_t)b * N_;
  for (int q = tid; q < (TA + 20) / 4; q += NTHR) {
    const int i = q * 4;
    const int n = m0 + i;
    float4 v;
    if (n + 3 < N_) {
      v = *(const float4*)(rrow + n);
    } else {
      v.x = (n     < N_) ? rrow[n]     : 0.f;
      v.y = (n + 1 < N_) ? rrow[n + 1] : 0.f;
      v.z = (n + 2 < N_) ? rrow[n + 2] : 0.f;
      v.w = (n + 3 < N_) ? rrow[n + 3] : 0.f;
    }
    *(float4*)&rs[i] = v;
  }
  __syncthreads();

  const int m = m0 + tid * 4;
  if (m >= M_) return;

  float w[24];
  #pragma unroll
  for (int k = 0; k < 6; ++k) {
    const float4 v = *(const float4*)&rs[tid * 4 + k * 4];
    w[k*4] = v.x; w[k*4+1] = v.y; w[k*4+2] = v.z; w[k*4+3] = v.w;
  }

  for (int cl = 0; cl < CGB; ++cl) {
    const int c = c0 + cl;
    const size_t base = ((size_t)(b * C_ + c)) * M_ + m;
    float g[4] = {0.f, 0.f, 0.f, 0.f};
    const float* hr = hs[cl];
    #pragma unroll
    for (int j = 0; j < K_; ++j) {
      const float h = hr[j];
      g[0] = fmaf(h, w[j],     g[0]);
      g[1] = fmaf(h, w[j + 1], g[1]);
      g[2] = fmaf(h, w[j + 2], g[2]);
      g[3] = fmaf(h, w[j + 3], g[3]);
    }
    float xt[4] = {0.f,0.f,0.f,0.f}, xo[4] = {0.f,0.f,0.f,0.f};
    if (!first) {
      const float4 a = *(const float4*)(XT + base);
      const float4 o = *(const float4*)(XN + base);
      xt[0]=a.x; xt[1]=a.y; xt[2]=a.z; xt[3]=a.w;
      xo[0]=o.x; xo[1]=o.y; xo[2]=o.z; xo[3]=o.w;
    }
    float xn[4], xtn[4];
    #pragma unroll
    for (int r = 0; r < 4; ++r) {
      const float v = fmaf(g[r], 0.1f, xt[r]) - 0.01f;
      xn[r]  = v > 0.f ? v : 0.f;
      xtn[r] = xn[r] + beta * (xn[r] - xo[r]);
    }
    *(float4*)(XN + base) = make_float4(xn[0], xn[1], xn[2], xn[3]);
    *(float4*)(XT + base) = make_float4(xtn[0], xtn[1], xtn[2], xtn[3]);
  }
}

extern "C" void kernel_launch(void* const* d_in, const int* in_sizes, int n_in,
                              void* d_out, int out_size, void* d_ws, size_t ws_size,
                              hipStream_t stream)
{
  const float* y = (const float*)d_in[0];   // [B,1,N] fp32
  const float* H = (const float*)d_in[1];   // [C,1,K] fp32
  float* out  = (float*)d_out;
  float* outy = out;                         // [B,N] y_hat region
  float* outx = out + (size_t)B_ * N_;       // [B,C,M] x region

  const size_t SZ = (size_t)B_ * C_ * M_;    // floats per x buffer

  // FISTA momentum scalars: betas[t] = (s_t - 1)/s_{t+1}, s_0 = 1  (betas[0]=0)
  float betas[T_];
  double s = 1.0;
  for (int t = 0; t < T_; ++t) {
    const double sn = (1.0 + sqrt(1.0 + 4.0 * s * s)) * 0.5;
    betas[t] = (float)((s - 1.0) / sn);
    s = sn;
  }

  const dim3 blk(NT);

  if (ws_size >= 2 * SZ * sizeof(float)) {
    // -------- fused path: 3 rotating x buffers, 402 MB/iter --------
    float* P[3] = { (float*)d_ws, (float*)d_ws + SZ, outx };
    const dim3 gF((M_ + TAF - 1) / TAF, B_);   // 70 x 32
    for (int t = 0; t < T_; ++t) {
      const float* Xc = P[(t + 2) % 3];        // x_t      (unused when t==0)
      const float* Xo = P[(t + 1) % 3];        // x_{t-1}  (unused when beta==0)
      float*       Xw = P[t % 3];              // x_{t+1}
      const float beta = (t >= 1) ? betas[t - 1] : 0.f;
      fused_step_kernel<<<gF, blk, 0, stream>>>(Xc, Xo, Xw, y, H, beta, t == 0);
    }
    // t=29 wrote P[2] == outx == x_30
    const dim3 gA(N_ / TA, B_);
    convT_kernel<<<gA, dim3(NTHR), 0, stream>>>(outx, y, H, outy, 0, 1.f);
  } else {
    // -------- fallback: round-1 two-kernel path --------
    float* RES = outy;
    float* XN  = outx;
    float* XT  = (float*)d_ws;
    const dim3 gA(N_ / TA, B_);
    const dim3 gB((M_ + TA - 1) / TA, B_, C_ / CGB);
    update_kernel<<<gB, dim3(NTHR), 0, stream>>>(y, H, XN, XT, betas[0], 1);
    for (int t = 1; t < T_; ++t) {
      convT_kernel<<<gA, dim3(NTHR), 0, stream>>>(XT, y, H, RES, 1, -1.f);
      update_kernel<<<gB, dim3(NTHR), 0, stream>>>(RES, H, XN, XT, betas[t], 0);
    }
    convT_kernel<<<gA, dim3(NTHR), 0, stream>>>(XN, y, H, RES, 0, 1.f);
  }
}